// Round 3
// baseline (202.885 us; speedup 1.0000x reference)
//
#include <hip/hip_runtime.h>
#include <stdint.h>

#define BB 4
#define SS 2048
#define DD 512
#define NTQ 32            // S/64 q-tiles per batch
#define NEG_BIG -1e30f
#define RESC_THR 4.0f     // defer-max threshold: p <= e^4, keeps f16 partials safe

typedef __attribute__((ext_vector_type(4))) float f32x4;
typedef __attribute__((ext_vector_type(8))) _Float16 f16x8;
typedef __attribute__((ext_vector_type(4))) _Float16 f16x4;

typedef __attribute__((address_space(1))) void GV;
typedef __attribute__((address_space(3))) void LV;

union PK4 { _Float16 h[4]; uint2 u; };

// ---------------------------------------------------------------------------
// Prep: K -> fp16 tile images in exact LDS byte layout (XOR swizzle baked in),
//       V -> transposed fp16 images, Q -> fp16 hi/lo linear arrays.
// One (b, 16-kv-tile) per block. Image per tile: [K 16KB][VT 16KB] = 32KB.
// ---------------------------------------------------------------------------
__global__ __launch_bounds__(256)
void prep_kernel(const float* __restrict__ K, const float* __restrict__ V,
                 const float* __restrict__ Q, char* __restrict__ PREP,
                 _Float16* __restrict__ Qh, _Float16* __restrict__ Ql)
{
  const int blk = blockIdx.x;
  const int b   = blk >> 7;
  const int j   = blk & 127;
  const int tid = threadIdx.x;
  char* img = PREP + (size_t)blk * 32768;

  // K image: rows 16 x 512 f16; byte off = rr*1024 + ((cc*2) ^ ((rr&7)<<4))
  #pragma unroll
  for (int i = 0; i < 8; ++i) {
    int chunk = tid + 256 * i;
    int rr = chunk >> 7;
    int cc = (chunk & 127) << 2;
    float4 a = *(const float4*)(K + ((size_t)(b * SS + j * 16 + rr)) * DD + cc);
    PK4 p; p.h[0] = (_Float16)a.x; p.h[1] = (_Float16)a.y;
           p.h[2] = (_Float16)a.z; p.h[3] = (_Float16)a.w;
    int off = rr * 1024 + ((cc * 2) ^ ((rr & 7) << 4));
    *(uint2*)(img + off) = p.u;
  }

  // VT image: [512 d][16 kq] f16; byte off = 16384 + d*32 + ((kq4*8)^(((d>>2)&1)<<4))
  #pragma unroll
  for (int half = 0; half < 2; ++half) {
    int d = tid + 256 * half;
    const float* vp = V + ((size_t)(b * SS + j * 16)) * DD + d;
    int swz = ((d >> 2) & 1) << 4;
    #pragma unroll
    for (int kq4 = 0; kq4 < 4; ++kq4) {
      PK4 p;
      p.h[0] = (_Float16)vp[(kq4 * 4 + 0) * DD];
      p.h[1] = (_Float16)vp[(kq4 * 4 + 1) * DD];
      p.h[2] = (_Float16)vp[(kq4 * 4 + 2) * DD];
      p.h[3] = (_Float16)vp[(kq4 * 4 + 3) * DD];
      *(uint2*)(img + 16384 + d * 32 + ((kq4 * 8) ^ swz)) = p.u;
    }
  }

  // Q hi/lo fp16, linear [b][s][d]
  #pragma unroll
  for (int i = 0; i < 8; ++i) {
    int chunk = tid + 256 * i;
    int rr = chunk >> 7;
    int cc = (chunk & 127) << 2;
    size_t base = ((size_t)(b * SS + j * 16 + rr)) * DD + cc;
    float4 a = *(const float4*)(Q + base);
    PK4 ph, pl;
    float xv[4] = {a.x, a.y, a.z, a.w};
    #pragma unroll
    for (int e = 0; e < 4; ++e) {
      _Float16 hh = (_Float16)xv[e];
      ph.h[e] = hh;
      pl.h[e] = (_Float16)(xv[e] - (float)hh);
    }
    *(uint2*)(Qh + base) = ph.u;
    *(uint2*)(Ql + base) = pl.u;
  }
}

// ---------------------------------------------------------------------------
// Flash attention, prepped-fp16 path.
// Block = 4 waves x 16 q rows. Per 16-kv tile: QK = 16 ds_read_b128 + 32 MFMA
// (16x16x32_f16, 2-pass hi/lo); PV = 32 ds_read_b64 + 32 MFMA (16x16x16f16,
// P frag is in-lane — no shuffles). Double-buffered async staging via
// global_load_lds, one barrier per tile, defer-max rescale.
// ---------------------------------------------------------------------------
__global__ __launch_bounds__(256, 2)
void attn_kernel(const char* __restrict__ PREP, const _Float16* __restrict__ Qh,
                 const _Float16* __restrict__ Ql, _Float16* __restrict__ Opart,
                 float* __restrict__ MLp, float* __restrict__ Out,
                 int R, int direct)
{
  __shared__ char smem[2][32768];   // [K 16KB][VT 16KB] per buffer

  const int tid = threadIdx.x;
  const int ln  = tid & 63;
  const int w   = tid >> 6;
  const int m   = ln & 15;
  const int g   = ln >> 4;

  const int u    = blockIdx.x;
  const int tIdx = u / (BB * R);
  const int t    = (NTQ - 1) - tIdx;   // longest first
  const int rem  = u % (BB * R);
  const int b    = rem / R;
  const int r    = rem % R;

  const int T16 = 4 * (t + 1);
  const int C   = 2 * ((T16 + 2 * R - 1) / (2 * R));
  const int j0  = r * C;
  const int j1  = min(j0 + C, T16);
  const int nt  = j1 - j0;

  const int qrow  = t * 64 + w * 16 + m;
  const int qmaxw = t * 64 + w * 16 + 15;   // wave's largest q row

  // Q fragments (fp16 hi/lo) from prepped arrays
  f16x8 qh[16], ql[16];
  {
    const _Float16* qhp = Qh + ((size_t)(b * SS + qrow)) * DD + g * 8;
    const _Float16* qlp = Ql + ((size_t)(b * SS + qrow)) * DD + g * 8;
    #pragma unroll
    for (int ks = 0; ks < 16; ++ks) {
      qh[ks] = *(const f16x8*)(qhp + ks * 32);
      ql[ks] = *(const f16x8*)(qlp + ks * 32);
    }
  }

  f32x4 acc[32];
  {
    f32x4 z = {0.f, 0.f, 0.f, 0.f};
    #pragma unroll
    for (int i = 0; i < 32; ++i) acc[i] = z;
  }
  float mst = NEG_BIG, lst = 0.f;

  const char* tilebase = PREP + (size_t)b * 128 * 32768;

  auto STAGE = [&](int bi, int jt) {
    const char* src = tilebase + (size_t)jt * 32768;
    #pragma unroll
    for (int i = 0; i < 8; ++i) {
      int o = (tid + i * 256) * 16;
      __builtin_amdgcn_global_load_lds((GV*)(src + o), (LV*)(smem[bi] + o),
                                       16, 0, 0);
    }
  };

  if (nt > 0) STAGE(0, j0);

  for (int jj = 0; jj < nt; ++jj) {
    const int cur = jj & 1;
    __syncthreads();                       // drains vmcnt -> buf[cur] ready
    if (jj + 1 < nt) STAGE(cur ^ 1, j0 + jj + 1);

    const int kv0 = (j0 + jj) * 16;
    if (kv0 <= qmaxw) {                    // causal early-out (wave-uniform)
      const char* kb = smem[cur];

      // ---- QK^T: S^T[kv][q], 2-pass fp16 ---------------------------------
      f32x4 s = {0.f, 0.f, 0.f, 0.f};
      {
        const char* krow = kb + m * 1024;
        const int rsw = (m & 7) << 4;
        __builtin_amdgcn_s_setprio(1);
        #pragma unroll
        for (int ks = 0; ks < 16; ++ks) {
          int off = (ks * 64 + g * 16) ^ rsw;
          f16x8 kf = *(const f16x8*)(krow + off);
          s = __builtin_amdgcn_mfma_f32_16x16x32_f16(kf, qh[ks], s, 0, 0, 0);
          s = __builtin_amdgcn_mfma_f32_16x16x32_f16(kf, ql[ks], s, 0, 0, 0);
        }
        __builtin_amdgcn_s_setprio(0);
      }

      // ---- online softmax (lane: kv = kv0+4g+r, q = qrow) -----------------
      float sv0 = (kv0 + 4 * g + 0 <= qrow) ? s[0] : NEG_BIG;
      float sv1 = (kv0 + 4 * g + 1 <= qrow) ? s[1] : NEG_BIG;
      float sv2 = (kv0 + 4 * g + 2 <= qrow) ? s[2] : NEG_BIG;
      float sv3 = (kv0 + 4 * g + 3 <= qrow) ? s[3] : NEG_BIG;
      float tm = fmaxf(fmaxf(sv0, sv1), fmaxf(sv2, sv3));
      tm = fmaxf(tm, __shfl_xor(tm, 16));
      tm = fmaxf(tm, __shfl_xor(tm, 32));

      float sc = 1.f;
      unsigned long long need = __ballot(tm > mst + RESC_THR);
      if (need) {                          // wave-uniform branch
        float mnew = fmaxf(mst, tm);
        sc = __expf(mst - mnew);
        mst = mnew;
        #pragma unroll
        for (int i = 0; i < 32; ++i) {
          acc[i][0] *= sc; acc[i][1] *= sc; acc[i][2] *= sc; acc[i][3] *= sc;
        }
      }
      float p0 = (kv0 + 4 * g + 0 <= qrow) ? __expf(sv0 - mst) : 0.f;
      float p1 = (kv0 + 4 * g + 1 <= qrow) ? __expf(sv1 - mst) : 0.f;
      float p2 = (kv0 + 4 * g + 2 <= qrow) ? __expf(sv2 - mst) : 0.f;
      float p3 = (kv0 + 4 * g + 3 <= qrow) ? __expf(sv3 - mst) : 0.f;
      float rs = p0 + p1 + p2 + p3;
      rs += __shfl_xor(rs, 16);
      rs += __shfl_xor(rs, 32);
      lst = lst * sc + rs;

      // ---- PV: O^T += V^T * P^T; P frag is in-lane (k=4g+e, n=m) ----------
      f16x4 pf;
      pf[0] = (_Float16)p0; pf[1] = (_Float16)p1;
      pf[2] = (_Float16)p2; pf[3] = (_Float16)p3;
      const char* vb = kb + 16384;
      __builtin_amdgcn_s_setprio(1);
      #pragma unroll
      for (int dt = 0; dt < 32; ++dt) {
        int d = dt * 16 + m;
        int off = d * 32 + ((g * 8) ^ (((d >> 2) & 1) << 4));
        f16x4 vf = *(const f16x4*)(vb + off);
        acc[dt] = __builtin_amdgcn_mfma_f32_16x16x16f16(vf, pf, acc[dt], 0, 0, 0);
      }
      __builtin_amdgcn_s_setprio(0);
    }
  }

  // ---- epilogue -------------------------------------------------------------
  if (!direct && ln < 16) {
    float* mlp = MLp + ((size_t)u * 64 + w * 16 + m) * 2;
    mlp[0] = mst; mlp[1] = lst;
  }

  if (direct) {
    float inv = 1.0f / lst;
    float* orow = Out + ((size_t)(b * SS + qrow)) * 1024 + 512;
    #pragma unroll
    for (int dt = 0; dt < 32; ++dt) {
      float4 v4;
      v4.x = acc[dt][0] * inv; v4.y = acc[dt][1] * inv;
      v4.z = acc[dt][2] * inv; v4.w = acc[dt][3] * inv;
      *(float4*)(orow + dt * 16 + g * 4) = v4;
    }
  } else {
    _Float16* orow = Opart + ((size_t)u * 64 + w * 16 + m) * DD;
    #pragma unroll
    for (int dt = 0; dt < 32; ++dt) {
      PK4 p;
      p.h[0] = (_Float16)acc[dt][0]; p.h[1] = (_Float16)acc[dt][1];
      p.h[2] = (_Float16)acc[dt][2]; p.h[3] = (_Float16)acc[dt][3];
      *(uint2*)(orow + dt * 16 + g * 4) = p.u;
    }
  }
}

__global__ __launch_bounds__(256)
void combine_kernel(const _Float16* __restrict__ Opart, const float* __restrict__ MLp,
                    const float* __restrict__ orig, float* __restrict__ Out, int R)
{
  int gid = blockIdx.x * 256 + threadIdx.x;
  int row = gid >> 7;
  int c4  = (gid & 127) << 2;
  int b = row >> 11;
  int s = row & 2047;
  int t = s >> 6;
  int qloc = s & 63;

  // copy original into out[..., 0:512]
  *(float4*)(Out + (size_t)row * 1024 + c4) = *(const float4*)(orig + (size_t)row * 512 + c4);

  int ubase = (NTQ - 1 - t) * (BB * R) + b * R;
  float mr[4] = {NEG_BIG, NEG_BIG, NEG_BIG, NEG_BIG};
  float lr[4] = {0.f, 0.f, 0.f, 0.f};
  #pragma unroll
  for (int rr = 0; rr < 4; ++rr) {
    if (rr < R) {
      const float* p = MLp + ((size_t)(ubase + rr) * 64 + qloc) * 2;
      mr[rr] = p[0]; lr[rr] = p[1];
    }
  }
  float M = fmaxf(fmaxf(mr[0], mr[1]), fmaxf(mr[2], mr[3]));
  float L = 0.f, a0 = 0.f, a1 = 0.f, a2 = 0.f, a3 = 0.f;
  #pragma unroll
  for (int rr = 0; rr < 4; ++rr) {
    if (rr < R && mr[rr] > -5e29f) {
      float wgt = __expf(mr[rr] - M);
      L += wgt * lr[rr];
      const _Float16* op = Opart + ((size_t)(ubase + rr) * 64 + qloc) * 512 + c4;
      f16x4 ov = *(const f16x4*)(op);
      a0 += wgt * (float)ov[0]; a1 += wgt * (float)ov[1];
      a2 += wgt * (float)ov[2]; a3 += wgt * (float)ov[3];
    }
  }
  float inv = 1.0f / L;
  float4 r4; r4.x = a0 * inv; r4.y = a1 * inv; r4.z = a2 * inv; r4.w = a3 * inv;
  *(float4*)(Out + (size_t)row * 1024 + 512 + c4) = r4;
}

__global__ __launch_bounds__(256)
void copy_orig(const float* __restrict__ orig, float* __restrict__ Out)
{
  int gid = blockIdx.x * 256 + threadIdx.x;
  int row = gid >> 7;
  int c4  = (gid & 127) << 2;
  *(float4*)(Out + (size_t)row * 1024 + c4) = *(const float4*)(orig + (size_t)row * 512 + c4);
}

extern "C" void kernel_launch(void* const* d_in, const int* in_sizes, int n_in,
                              void* d_out, int out_size, void* d_ws, size_t ws_size,
                              hipStream_t stream)
{
  (void)in_sizes; (void)n_in; (void)out_size;
  const float* keys     = (const float*)d_in[0];
  const float* queries  = (const float*)d_in[1];
  const float* values   = (const float*)d_in[2];
  const float* original = (const float*)d_in[3];
  float* out = (float*)d_out;

  const size_t PREPB = (size_t)BB * 128 * 32768;     // 16 MiB tile images
  const size_t QHB   = (size_t)BB * SS * DD * 2;     // 8 MiB each (Qh, Ql)
  const size_t prepTotal = PREPB + 2 * QHB;          // 33,554,432
  const size_t perR = (size_t)128 * 64 * DD * 2 + (size_t)128 * 64 * 2 * 4; // Opart+MLp per R

  int R = 1;
  if      (ws_size >= prepTotal + 4 * perR) R = 4;   // 67,371,008 (fits per round-1)
  else if (ws_size >= prepTotal + 2 * perR) R = 2;

  char* PREP = (char*)d_ws;
  _Float16* Qh = (_Float16*)(PREP + PREPB);
  _Float16* Ql = (_Float16*)(PREP + PREPB + QHB);
  _Float16* Opart = (_Float16*)(PREP + prepTotal);
  float* MLp = (float*)(PREP + prepTotal + (size_t)R * 128 * 64 * DD * 2);
  const int direct = (R == 1) ? 1 : 0;
  const int NU = NTQ * BB * R;

  hipLaunchKernelGGL(prep_kernel, dim3(BB * 128), dim3(256), 0, stream,
                     keys, values, queries, PREP, Qh, Ql);

  hipLaunchKernelGGL(attn_kernel, dim3(NU), dim3(256), 0, stream,
                     PREP, Qh, Ql, Opart, MLp, out, R, direct);

  const int cgrid = (BB * SS * 128) / 256;   // 4096 blocks
  if (!direct)
    hipLaunchKernelGGL(combine_kernel, dim3(cgrid), dim3(256), 0, stream,
                       Opart, MLp, original, out, R);
  else
    hipLaunchKernelGGL(copy_orig, dim3(cgrid), dim3(256), 0, stream, original, out);
}

// Round 4
// 128.190 us; speedup vs baseline: 1.5827x; 1.5827x over previous
//
#include <hip/hip_runtime.h>
#include <stdint.h>

#define BB 4
#define SS 2048
#define DD 512
#define NTQ 32            // S/64 q-tiles per batch
#define NEG_BIG -1e30f
#define RESC_THR 4.0f     // defer-max threshold

typedef __attribute__((ext_vector_type(4))) float f32x4;
typedef __attribute__((ext_vector_type(8))) _Float16 f16x8;
typedef __attribute__((ext_vector_type(4))) _Float16 f16x4;

typedef __attribute__((address_space(1))) void GV;
typedef __attribute__((address_space(3))) void LV;

union PK4 { _Float16 h[4]; uint2 u; };

// ---------------------------------------------------------------------------
// Prep: K -> fp16 tile images in exact LDS byte layout (XOR swizzle baked in),
//       V -> transposed fp16 images. One (b, 16-kv-tile) per block.
// Image per tile: [K 16KB][VT 16KB] = 32KB. Total 16 MiB.
// ---------------------------------------------------------------------------
__global__ __launch_bounds__(256)
void prep_kernel(const float* __restrict__ K, const float* __restrict__ V,
                 char* __restrict__ PREP)
{
  const int blk = blockIdx.x;
  const int b   = blk >> 7;
  const int j   = blk & 127;
  const int tid = threadIdx.x;
  char* img = PREP + (size_t)blk * 32768;

  // K image: byte off = rr*1024 + ((cc*2) ^ ((rr&7)<<4))
  #pragma unroll
  for (int i = 0; i < 8; ++i) {
    int chunk = tid + 256 * i;
    int rr = chunk >> 7;
    int cc = (chunk & 127) << 2;
    float4 a = *(const float4*)(K + ((size_t)(b * SS + j * 16 + rr)) * DD + cc);
    PK4 p; p.h[0] = (_Float16)a.x; p.h[1] = (_Float16)a.y;
           p.h[2] = (_Float16)a.z; p.h[3] = (_Float16)a.w;
    int off = rr * 1024 + ((cc * 2) ^ ((rr & 7) << 4));
    *(uint2*)(img + off) = p.u;
  }

  // VT image: byte off = 16384 + d*32 + ((kq4*8) ^ (((d>>2)&1)<<4))
  #pragma unroll
  for (int half = 0; half < 2; ++half) {
    int d = tid + 256 * half;
    const float* vp = V + ((size_t)(b * SS + j * 16)) * DD + d;
    int swz = ((d >> 2) & 1) << 4;
    #pragma unroll
    for (int kq4 = 0; kq4 < 4; ++kq4) {
      PK4 p;
      p.h[0] = (_Float16)vp[(kq4 * 4 + 0) * DD];
      p.h[1] = (_Float16)vp[(kq4 * 4 + 1) * DD];
      p.h[2] = (_Float16)vp[(kq4 * 4 + 2) * DD];
      p.h[3] = (_Float16)vp[(kq4 * 4 + 3) * DD];
      *(uint2*)(img + 16384 + d * 32 + ((kq4 * 8) ^ swz)) = p.u;
    }
  }
}

// ---------------------------------------------------------------------------
// Flash attention over fixed-size kv chunks.
// Unit = (t, b, r): q rows [64t, 64t+64), kv tiles [r*CT, min((r+1)*CT, T16)).
// CT = 4G tiles (G = 1<<lg). R_t = t/G + 1 units per (t,b).
// Slot index (workspace): b*TU + OFF(t) + r, OFF(t) = t + G*a*(a-1)/2 + a*(t%G).
// Block = 4 waves x 16 q rows; per tile: QK 16 MFMA (16x16x32 f16, 1-pass),
// PV 32 MFMA (16x16x16f16). Double-buffered global_load_lds staging.
// ---------------------------------------------------------------------------
__global__ __launch_bounds__(256, 2)
void attn_kernel(const char* __restrict__ PREP, const float* __restrict__ Qg,
                 _Float16* __restrict__ Opart, float* __restrict__ MLp,
                 float* __restrict__ Out,
                 int lg, int TU, int Rmax, int direct)
{
  __shared__ char smem[2][32768];   // [K 16KB][VT 16KB] per buffer

  const int tid = threadIdx.x;
  const int ln  = tid & 63;
  const int w   = tid >> 6;
  const int m   = ln & 15;
  const int g   = ln >> 4;

  const int u = blockIdx.x;
  int t, b, r;
  if (direct) {
    t = (NTQ - 1) - (u / BB);
    b = u % BB;
    r = 0;
  } else {
    const int per = BB * Rmax;
    t = (NTQ - 1) - (u / per);
    const int rem = u % per;
    b = rem / Rmax;
    r = rem % Rmax;
  }

  const int T16 = 4 * (t + 1);
  const int G   = 1 << lg;
  const int Rt  = (t >> lg) + 1;
  if (!direct && r >= Rt) return;          // inactive slot, whole block exits

  const int CT = direct ? T16 : (4 << lg);
  const int j0 = r * CT;
  const int j1 = min(j0 + CT, T16);
  const int nt = j1 - j0;

  int slot = 0;
  if (!direct) {
    const int a  = t >> lg;
    const int bb = t & (G - 1);
    const int OFF = t + G * (a * (a - 1) / 2) + a * bb;
    slot = b * TU + OFF + r;
  }

  const int qrow  = t * 64 + w * 16 + m;
  const int qmaxw = t * 64 + w * 16 + 15;

  // ---- Q fp32 -> fp16 fragments (once per block) ---------------------------
  f16x8 qf[16];
  {
    const float* qp = Qg + ((size_t)(b * SS + qrow)) * DD + g * 8;
    #pragma unroll
    for (int ks = 0; ks < 16; ++ks) {
      float4 a0 = *(const float4*)(qp + ks * 32);
      float4 a1 = *(const float4*)(qp + ks * 32 + 4);
      f16x8 v;
      v[0] = (_Float16)a0.x; v[1] = (_Float16)a0.y;
      v[2] = (_Float16)a0.z; v[3] = (_Float16)a0.w;
      v[4] = (_Float16)a1.x; v[5] = (_Float16)a1.y;
      v[6] = (_Float16)a1.z; v[7] = (_Float16)a1.w;
      qf[ks] = v;
    }
  }

  f32x4 acc[32];
  {
    f32x4 z = {0.f, 0.f, 0.f, 0.f};
    #pragma unroll
    for (int i = 0; i < 32; ++i) acc[i] = z;
  }
  float mst = NEG_BIG, lst = 0.f;

  const char* tilebase = PREP + (size_t)b * 128 * 32768;

  auto STAGE = [&](int bi, int jt) {
    const char* src = tilebase + (size_t)jt * 32768;
    #pragma unroll
    for (int i = 0; i < 8; ++i) {
      int o = (tid + i * 256) * 16;
      __builtin_amdgcn_global_load_lds((GV*)(src + o), (LV*)(smem[bi] + o),
                                       16, 0, 0);
    }
  };

  STAGE(0, j0);

  for (int jj = 0; jj < nt; ++jj) {
    const int cur = jj & 1;
    __syncthreads();                       // buf[cur] staged (issued last iter)
    if (jj + 1 < nt) STAGE(cur ^ 1, j0 + jj + 1);

    const int kv0 = (j0 + jj) * 16;
    if (kv0 <= qmaxw) {                    // causal early-out (wave-uniform)
      const char* kb = smem[cur];

      // ---- QK^T: S^T[kv][q], single-pass fp16 -----------------------------
      f32x4 s = {0.f, 0.f, 0.f, 0.f};
      {
        const char* krow = kb + m * 1024;
        const int rsw = (m & 7) << 4;
        __builtin_amdgcn_s_setprio(1);
        #pragma unroll
        for (int ks = 0; ks < 16; ++ks) {
          int off = (ks * 64 + g * 16) ^ rsw;
          f16x8 kf = *(const f16x8*)(krow + off);
          s = __builtin_amdgcn_mfma_f32_16x16x32_f16(kf, qf[ks], s, 0, 0, 0);
        }
        __builtin_amdgcn_s_setprio(0);
      }

      // ---- online softmax (lane: kv = kv0+4g+e, q = qrow) -----------------
      float sv0 = (kv0 + 4 * g + 0 <= qrow) ? s[0] : NEG_BIG;
      float sv1 = (kv0 + 4 * g + 1 <= qrow) ? s[1] : NEG_BIG;
      float sv2 = (kv0 + 4 * g + 2 <= qrow) ? s[2] : NEG_BIG;
      float sv3 = (kv0 + 4 * g + 3 <= qrow) ? s[3] : NEG_BIG;
      float tm = fmaxf(fmaxf(sv0, sv1), fmaxf(sv2, sv3));
      tm = fmaxf(tm, __shfl_xor(tm, 16));
      tm = fmaxf(tm, __shfl_xor(tm, 32));

      float sc = 1.f;
      unsigned long long need = __ballot(tm > mst + RESC_THR);
      if (need) {                          // wave-uniform, rare (defer-max)
        float mnew = fmaxf(mst, tm);
        sc = __expf(mst - mnew);
        mst = mnew;
        #pragma unroll
        for (int i = 0; i < 32; ++i) {
          acc[i][0] *= sc; acc[i][1] *= sc; acc[i][2] *= sc; acc[i][3] *= sc;
        }
      }
      float p0 = (kv0 + 4 * g + 0 <= qrow) ? __expf(sv0 - mst) : 0.f;
      float p1 = (kv0 + 4 * g + 1 <= qrow) ? __expf(sv1 - mst) : 0.f;
      float p2 = (kv0 + 4 * g + 2 <= qrow) ? __expf(sv2 - mst) : 0.f;
      float p3 = (kv0 + 4 * g + 3 <= qrow) ? __expf(sv3 - mst) : 0.f;
      float rs = p0 + p1 + p2 + p3;
      rs += __shfl_xor(rs, 16);
      rs += __shfl_xor(rs, 32);
      lst = lst * sc + rs;

      // ---- PV: O^T += V^T * P^T; P frag in-lane (k=4g+e, n=m) -------------
      f16x4 pf;
      pf[0] = (_Float16)p0; pf[1] = (_Float16)p1;
      pf[2] = (_Float16)p2; pf[3] = (_Float16)p3;
      const char* vb = kb + 16384;
      __builtin_amdgcn_s_setprio(1);
      #pragma unroll
      for (int dt = 0; dt < 32; ++dt) {
        int d = dt * 16 + m;
        int off = d * 32 + ((g * 8) ^ (((d >> 2) & 1) << 4));
        f16x4 vf = *(const f16x4*)(vb + off);
        acc[dt] = __builtin_amdgcn_mfma_f32_16x16x16f16(vf, pf, acc[dt], 0, 0, 0);
      }
      __builtin_amdgcn_s_setprio(0);
    }
  }

  // ---- epilogue -------------------------------------------------------------
  if (direct) {
    float inv = 1.0f / lst;
    float* orow = Out + ((size_t)(b * SS + qrow)) * 1024 + 512;
    #pragma unroll
    for (int dt = 0; dt < 32; ++dt) {
      float4 v4;
      v4.x = acc[dt][0] * inv; v4.y = acc[dt][1] * inv;
      v4.z = acc[dt][2] * inv; v4.w = acc[dt][3] * inv;
      *(float4*)(orow + dt * 16 + g * 4) = v4;
    }
  } else {
    if (ln < 16) {
      float* mlp = MLp + ((size_t)slot * 64 + w * 16 + m) * 2;
      mlp[0] = mst; mlp[1] = lst;
    }
    _Float16* orow = Opart + ((size_t)slot * 64 + w * 16 + m) * DD;
    #pragma unroll
    for (int dt = 0; dt < 32; ++dt) {
      PK4 p;
      p.h[0] = (_Float16)acc[dt][0]; p.h[1] = (_Float16)acc[dt][1];
      p.h[2] = (_Float16)acc[dt][2]; p.h[3] = (_Float16)acc[dt][3];
      *(uint2*)(orow + dt * 16 + g * 4) = p.u;
    }
  }
}

__global__ __launch_bounds__(256)
void combine_kernel(const _Float16* __restrict__ Opart, const float* __restrict__ MLp,
                    const float* __restrict__ orig, float* __restrict__ Out,
                    int lg, int TU)
{
  int gid = blockIdx.x * 256 + threadIdx.x;
  int row = gid >> 7;
  int c4  = (gid & 127) << 2;
  int b = row >> 11;
  int s = row & 2047;
  int t = s >> 6;
  int qloc = s & 63;

  // copy original into out[..., 0:512]
  *(float4*)(Out + (size_t)row * 1024 + c4) = *(const float4*)(orig + (size_t)row * 512 + c4);

  const int G  = 1 << lg;
  const int a  = t >> lg;
  const int Rt = a + 1;
  const int OFF = t + G * (a * (a - 1) / 2) + a * (t & (G - 1));
  const size_t base = (size_t)b * TU + OFF;

  float mr[8], lr[8];
  #pragma unroll
  for (int rr = 0; rr < 8; ++rr) { mr[rr] = NEG_BIG; lr[rr] = 0.f; }
  #pragma unroll
  for (int rr = 0; rr < 8; ++rr) {
    if (rr < Rt) {
      const float* p = MLp + ((base + rr) * 64 + qloc) * 2;
      mr[rr] = p[0]; lr[rr] = p[1];
    }
  }
  float M = NEG_BIG;
  #pragma unroll
  for (int rr = 0; rr < 8; ++rr) M = fmaxf(M, mr[rr]);

  float L = 0.f, a0 = 0.f, a1 = 0.f, a2 = 0.f, a3 = 0.f;
  #pragma unroll
  for (int rr = 0; rr < 8; ++rr) {
    if (rr < Rt && mr[rr] > -5e29f) {
      float wgt = __expf(mr[rr] - M);
      L += wgt * lr[rr];
      const _Float16* op = Opart + ((base + rr) * 64 + qloc) * 512 + c4;
      f16x4 ov = *(const f16x4*)(op);
      a0 += wgt * (float)ov[0]; a1 += wgt * (float)ov[1];
      a2 += wgt * (float)ov[2]; a3 += wgt * (float)ov[3];
    }
  }
  float inv = 1.0f / L;
  float4 r4; r4.x = a0 * inv; r4.y = a1 * inv; r4.z = a2 * inv; r4.w = a3 * inv;
  *(float4*)(Out + (size_t)row * 1024 + 512 + c4) = r4;
}

__global__ __launch_bounds__(256)
void copy_orig(const float* __restrict__ orig, float* __restrict__ Out)
{
  int gid = blockIdx.x * 256 + threadIdx.x;
  int row = gid >> 7;
  int c4  = (gid & 127) << 2;
  *(float4*)(Out + (size_t)row * 1024 + c4) = *(const float4*)(orig + (size_t)row * 512 + c4);
}

extern "C" void kernel_launch(void* const* d_in, const int* in_sizes, int n_in,
                              void* d_out, int out_size, void* d_ws, size_t ws_size,
                              hipStream_t stream)
{
  (void)in_sizes; (void)n_in; (void)out_size;
  const float* keys     = (const float*)d_in[0];
  const float* queries  = (const float*)d_in[1];
  const float* values   = (const float*)d_in[2];
  const float* original = (const float*)d_in[3];
  float* out = (float*)d_out;

  const size_t PREPB = (size_t)BB * 128 * 32768;   // 16,777,216

  // Tier ladder: G=4 (CT=16 tiles), G=8 (CT=32), G=16 (CT=64), direct.
  // TU(G) = 32 + G*a(a-1)/2 closed form evaluated: 144 / 80 / 48.
  const int TUs[3]   = {144, 80, 48};
  const int lgs[3]   = {2, 3, 4};
  const int Rmaxs[3] = {8, 4, 2};

  int lg = -1, TU = 0, Rmax = 1, direct = 1;
  for (int i = 0; i < 3; ++i) {
    size_t need = PREPB + (size_t)BB * TUs[i] * (64 * 512 * 2)   // Opart fp16
                        + (size_t)BB * TUs[i] * (64 * 8);        // MLp fp32
    if (ws_size >= need) { lg = lgs[i]; TU = TUs[i]; Rmax = Rmaxs[i]; direct = 0; break; }
  }

  char* PREP = (char*)d_ws;
  _Float16* Opart = (_Float16*)(PREP + PREPB);
  float* MLp = (float*)(PREP + PREPB + (size_t)BB * TU * (64 * 512 * 2));

  hipLaunchKernelGGL(prep_kernel, dim3(BB * 128), dim3(256), 0, stream,
                     keys, values, PREP);

  const int grid = direct ? (NTQ * BB) : (NTQ * BB * Rmax);
  hipLaunchKernelGGL(attn_kernel, dim3(grid), dim3(256), 0, stream,
                     PREP, queries, Opart, MLp, out, (lg < 0 ? 4 : lg), TU, Rmax, direct);

  const int cgrid = (BB * SS * 128) / 256;   // 4096 blocks
  if (!direct)
    hipLaunchKernelGGL(combine_kernel, dim3(cgrid), dim3(256), 0, stream,
                       Opart, MLp, original, out, lg, TU);
  else
    hipLaunchKernelGGL(copy_orig, dim3(cgrid), dim3(256), 0, stream, original, out);
}

// Round 5
// 108.671 us; speedup vs baseline: 1.8670x; 1.1796x over previous
//
#include <hip/hip_runtime.h>
#include <stdint.h>

#define BB 4
#define SS 2048
#define DD 512
#define NTQ 32            // S/64 q-tiles per batch
#define NEG_BIG -1e30f
#define RESC_THR 4.0f     // defer-max threshold

typedef __attribute__((ext_vector_type(4))) float f32x4;
typedef __attribute__((ext_vector_type(8))) _Float16 f16x8;
typedef __attribute__((ext_vector_type(4))) _Float16 f16x4;

typedef __attribute__((address_space(1))) void GV;
typedef __attribute__((address_space(3))) void LV;

union PK4 { _Float16 h[4]; uint2 u; };

// chunks per q-tile t for chunk size CC (in 16-kv tiles)
__device__ __host__ __forceinline__ int rt_of(int t, int CC) {
  return (4 * (t + 1) + CC - 1) / CC;
}

// ---------------------------------------------------------------------------
// Prep: K -> fp16 tile images in exact LDS byte layout (XOR swizzle baked in),
//       V -> transposed fp16 images. One (b, 16-kv-tile) per block.
// Image per tile: [K 16KB][VT 16KB] = 32KB. Total 16 MiB.
// V slot map: byte = d*32 + 8*(kq4 ^ ((d>>2)&3))  -- bijective over the 16
// 8B slots per 128B for any 16 consecutive d => conflict-free b64 read/write.
// ---------------------------------------------------------------------------
__global__ __launch_bounds__(256)
void prep_kernel(const float* __restrict__ K, const float* __restrict__ V,
                 char* __restrict__ PREP)
{
  const int blk = blockIdx.x;
  const int b   = blk >> 7;
  const int j   = blk & 127;
  const int tid = threadIdx.x;
  char* img = PREP + (size_t)blk * 32768;

  // K image: byte off = rr*1024 + ((cc*2) ^ ((rr&7)<<4))
  #pragma unroll
  for (int i = 0; i < 8; ++i) {
    int chunk = tid + 256 * i;
    int rr = chunk >> 7;
    int cc = (chunk & 127) << 2;
    float4 a = *(const float4*)(K + ((size_t)(b * SS + j * 16 + rr)) * DD + cc);
    PK4 p; p.h[0] = (_Float16)a.x; p.h[1] = (_Float16)a.y;
           p.h[2] = (_Float16)a.z; p.h[3] = (_Float16)a.w;
    int off = rr * 1024 + ((cc * 2) ^ ((rr & 7) << 4));
    *(uint2*)(img + off) = p.u;
  }

  // VT image: byte off = 16384 + d*32 + 8*(kq4 ^ ((d>>2)&3))
  #pragma unroll
  for (int half = 0; half < 2; ++half) {
    int d = tid + 256 * half;
    const float* vp = V + ((size_t)(b * SS + j * 16)) * DD + d;
    int vh = (d >> 2) & 3;
    #pragma unroll
    for (int kq4 = 0; kq4 < 4; ++kq4) {
      PK4 p;
      p.h[0] = (_Float16)vp[(kq4 * 4 + 0) * DD];
      p.h[1] = (_Float16)vp[(kq4 * 4 + 1) * DD];
      p.h[2] = (_Float16)vp[(kq4 * 4 + 2) * DD];
      p.h[3] = (_Float16)vp[(kq4 * 4 + 3) * DD];
      *(uint2*)(img + 16384 + d * 32 + 8 * (kq4 ^ vh)) = p.u;
    }
  }
}

// ---------------------------------------------------------------------------
// Flash attention over fixed-size kv chunks (CC 16-row tiles per chunk).
// Unit = (t, b, r). Units with Rt==1 write normalized output directly.
// Units with Rt>=2 write (O', m, l) to workspace slot b*TSLOT + OFF(t) + r,
// OFF(t) = sum of Rt' over t'<t with Rt'>=2.
// Block = 4 waves x 16 q rows; per tile: QK 16 MFMA (16x16x32 f16),
// PV 32 MFMA (16x16x16f16). Double-buffered global_load_lds staging.
// ---------------------------------------------------------------------------
__global__ __launch_bounds__(256, 2)
void attn_kernel(const char* __restrict__ PREP, const float* __restrict__ Qg,
                 _Float16* __restrict__ Opart, float* __restrict__ MLp,
                 float* __restrict__ Out, int CC, int TSLOT)
{
  __shared__ char smem[2][32768];   // [K 16KB][VT 16KB] per buffer

  const int tid = threadIdx.x;
  const int ln  = tid & 63;
  const int w   = tid >> 6;
  const int m   = ln & 15;
  const int g   = ln >> 4;

  // ---- decode blockIdx -> (t, b, r), t descending (longest chains first) ---
  int t = 0, b = 0, r = 0;
  {
    int u = blockIdx.x, base = 0;
    for (int tt = NTQ - 1; tt >= 0; --tt) {
      int rt = rt_of(tt, CC);
      int cnt = BB * rt;
      if (u < base + cnt) { int loc = u - base; t = tt; b = loc / rt; r = loc % rt; break; }
      base += cnt;
    }
  }
  const int Rt     = rt_of(t, CC);
  const int direct = (Rt == 1);

  const int T16 = 4 * (t + 1);
  const int j0  = r * CC;
  const int j1  = min(j0 + CC, T16);
  const int nt  = j1 - j0;          // >= 1 by construction

  int slot = 0;
  if (!direct) {
    int off = 0;
    for (int tt = 0; tt < t; ++tt) {
      int rt = rt_of(tt, CC);
      if (rt >= 2) off += rt;
    }
    slot = b * TSLOT + off + r;
  }

  const int qrow  = t * 64 + w * 16 + m;
  const int qmaxw = t * 64 + w * 16 + 15;

  // ---- Q fp32 -> fp16 fragments (once per block) ---------------------------
  f16x8 qf[16];
  {
    const float* qp = Qg + ((size_t)(b * SS + qrow)) * DD + g * 8;
    #pragma unroll
    for (int ks = 0; ks < 16; ++ks) {
      float4 a0 = *(const float4*)(qp + ks * 32);
      float4 a1 = *(const float4*)(qp + ks * 32 + 4);
      f16x8 v;
      v[0] = (_Float16)a0.x; v[1] = (_Float16)a0.y;
      v[2] = (_Float16)a0.z; v[3] = (_Float16)a0.w;
      v[4] = (_Float16)a1.x; v[5] = (_Float16)a1.y;
      v[6] = (_Float16)a1.z; v[7] = (_Float16)a1.w;
      qf[ks] = v;
    }
  }

  f32x4 acc[32];
  {
    f32x4 z = {0.f, 0.f, 0.f, 0.f};
    #pragma unroll
    for (int i = 0; i < 32; ++i) acc[i] = z;
  }
  float mst = NEG_BIG, lst = 0.f;

  const char* tilebase = PREP + (size_t)b * 128 * 32768;

  auto STAGE = [&](int bi, int jt) {
    const char* src = tilebase + (size_t)jt * 32768;
    #pragma unroll
    for (int i = 0; i < 8; ++i) {
      int o = (tid + i * 256) * 16;
      __builtin_amdgcn_global_load_lds((GV*)(src + o), (LV*)(smem[bi] + o),
                                       16, 0, 0);
    }
  };

  STAGE(0, j0);

  const int vh = (m >> 2) & 3;      // V slot xor key (per-lane const)

  for (int jj = 0; jj < nt; ++jj) {
    const int cur = jj & 1;
    __syncthreads();                       // buf[cur] staged (issued last iter)
    if (jj + 1 < nt) STAGE(cur ^ 1, j0 + jj + 1);

    const int kv0 = (j0 + jj) * 16;
    if (kv0 <= qmaxw) {                    // causal early-out (wave-uniform)
      const char* kb = smem[cur];

      // ---- QK^T: S^T[kv][q], single-pass fp16 -----------------------------
      f32x4 s = {0.f, 0.f, 0.f, 0.f};
      {
        const char* krow = kb + m * 1024;
        const int rsw = (m & 7) << 4;
        __builtin_amdgcn_s_setprio(1);
        #pragma unroll
        for (int ks = 0; ks < 16; ++ks) {
          int off = (ks * 64 + g * 16) ^ rsw;
          f16x8 kf = *(const f16x8*)(krow + off);
          s = __builtin_amdgcn_mfma_f32_16x16x32_f16(kf, qf[ks], s, 0, 0, 0);
        }
        __builtin_amdgcn_s_setprio(0);
      }

      // ---- online softmax (lane: kv = kv0+4g+e, q = qrow) -----------------
      float sv0 = (kv0 + 4 * g + 0 <= qrow) ? s[0] : NEG_BIG;
      float sv1 = (kv0 + 4 * g + 1 <= qrow) ? s[1] : NEG_BIG;
      float sv2 = (kv0 + 4 * g + 2 <= qrow) ? s[2] : NEG_BIG;
      float sv3 = (kv0 + 4 * g + 3 <= qrow) ? s[3] : NEG_BIG;
      float tm = fmaxf(fmaxf(sv0, sv1), fmaxf(sv2, sv3));
      tm = fmaxf(tm, __shfl_xor(tm, 16));
      tm = fmaxf(tm, __shfl_xor(tm, 32));

      float sc = 1.f;
      unsigned long long need = __ballot(tm > mst + RESC_THR);
      if (need) {                          // wave-uniform, rare (defer-max)
        float mnew = fmaxf(mst, tm);
        sc = __expf(mst - mnew);
        mst = mnew;
        #pragma unroll
        for (int i = 0; i < 32; ++i) {
          acc[i][0] *= sc; acc[i][1] *= sc; acc[i][2] *= sc; acc[i][3] *= sc;
        }
      }
      float p0 = (kv0 + 4 * g + 0 <= qrow) ? __expf(sv0 - mst) : 0.f;
      float p1 = (kv0 + 4 * g + 1 <= qrow) ? __expf(sv1 - mst) : 0.f;
      float p2 = (kv0 + 4 * g + 2 <= qrow) ? __expf(sv2 - mst) : 0.f;
      float p3 = (kv0 + 4 * g + 3 <= qrow) ? __expf(sv3 - mst) : 0.f;
      float rs = p0 + p1 + p2 + p3;
      rs += __shfl_xor(rs, 16);
      rs += __shfl_xor(rs, 32);
      lst = lst * sc + rs;

      // ---- PV: O^T += V^T * P^T; P frag in-lane (k=4g+e, n=m) -------------
      f16x4 pf;
      pf[0] = (_Float16)p0; pf[1] = (_Float16)p1;
      pf[2] = (_Float16)p2; pf[3] = (_Float16)p3;
      const char* vb = kb + 16384;
      __builtin_amdgcn_s_setprio(1);
      #pragma unroll
      for (int dt = 0; dt < 32; ++dt) {
        int d = dt * 16 + m;
        int off = d * 32 + 8 * (g ^ vh);
        f16x4 vf = *(const f16x4*)(vb + off);
        acc[dt] = __builtin_amdgcn_mfma_f32_16x16x16f16(vf, pf, acc[dt], 0, 0, 0);
      }
      __builtin_amdgcn_s_setprio(0);
    }
  }

  // ---- epilogue -------------------------------------------------------------
  if (direct) {
    float inv = 1.0f / lst;              // every row has kv=0..qrow valid
    float* orow = Out + ((size_t)(b * SS + qrow)) * 1024 + 512;
    #pragma unroll
    for (int dt = 0; dt < 32; ++dt) {
      float4 v4;
      v4.x = acc[dt][0] * inv; v4.y = acc[dt][1] * inv;
      v4.z = acc[dt][2] * inv; v4.w = acc[dt][3] * inv;
      *(float4*)(orow + dt * 16 + g * 4) = v4;
    }
  } else {
    if (ln < 16) {
      float* mlp = MLp + ((size_t)slot * 64 + w * 16 + m) * 2;
      mlp[0] = mst; mlp[1] = lst;
    }
    _Float16* orow = Opart + ((size_t)slot * 64 + w * 16 + m) * DD;
    #pragma unroll
    for (int dt = 0; dt < 32; ++dt) {
      PK4 p;
      p.h[0] = (_Float16)acc[dt][0]; p.h[1] = (_Float16)acc[dt][1];
      p.h[2] = (_Float16)acc[dt][2]; p.h[3] = (_Float16)acc[dt][3];
      *(uint2*)(orow + dt * 16 + g * 4) = p.u;
    }
  }
}

// ---------------------------------------------------------------------------
// Combine: copies original into out[:,:,0:512] for ALL rows; merges partial
// (O', m, l) slots for q-tiles with Rt >= 2 (Rt==1 rows were written direct).
// ---------------------------------------------------------------------------
__global__ __launch_bounds__(256)
void combine_kernel(const _Float16* __restrict__ Opart, const float* __restrict__ MLp,
                    const float* __restrict__ orig, float* __restrict__ Out,
                    int CC, int TSLOT)
{
  int gid = blockIdx.x * 256 + threadIdx.x;
  int row = gid >> 7;
  int c4  = (gid & 127) << 2;
  int b = row >> 11;
  int s = row & 2047;
  int t = s >> 6;
  int qloc = s & 63;

  // copy original into out[..., 0:512]
  *(float4*)(Out + (size_t)row * 1024 + c4) = *(const float4*)(orig + (size_t)row * 512 + c4);

  const int Rt = rt_of(t, CC);
  if (Rt < 2) return;                       // direct-written by attn_kernel

  int off = 0;
  for (int tt = 0; tt < t; ++tt) {
    int rt = rt_of(tt, CC);
    if (rt >= 2) off += rt;
  }
  const size_t base = (size_t)b * TSLOT + off;

  float mr[4], lr[4];
  #pragma unroll
  for (int rr = 0; rr < 4; ++rr) { mr[rr] = NEG_BIG; lr[rr] = 0.f; }
  #pragma unroll
  for (int rr = 0; rr < 4; ++rr) {
    if (rr < Rt) {
      const float* p = MLp + ((base + rr) * 64 + qloc) * 2;
      mr[rr] = p[0]; lr[rr] = p[1];
    }
  }
  float M = NEG_BIG;
  #pragma unroll
  for (int rr = 0; rr < 4; ++rr) M = fmaxf(M, mr[rr]);

  float L = 0.f, a0 = 0.f, a1 = 0.f, a2 = 0.f, a3 = 0.f;
  #pragma unroll
  for (int rr = 0; rr < 4; ++rr) {
    if (rr < Rt && mr[rr] > -5e29f) {       // skip rows empty in this chunk
      float wgt = __expf(mr[rr] - M);
      L += wgt * lr[rr];
      const _Float16* op = Opart + ((base + rr) * 64 + qloc) * 512 + c4;
      f16x4 ov = *(const f16x4*)(op);
      a0 += wgt * (float)ov[0]; a1 += wgt * (float)ov[1];
      a2 += wgt * (float)ov[2]; a3 += wgt * (float)ov[3];
    }
  }
  float inv = 1.0f / L;
  float4 r4; r4.x = a0 * inv; r4.y = a1 * inv; r4.z = a2 * inv; r4.w = a3 * inv;
  *(float4*)(Out + (size_t)row * 1024 + 512 + c4) = r4;
}

extern "C" void kernel_launch(void* const* d_in, const int* in_sizes, int n_in,
                              void* d_out, int out_size, void* d_ws, size_t ws_size,
                              hipStream_t stream)
{
  (void)in_sizes; (void)n_in; (void)out_size;
  const float* keys     = (const float*)d_in[0];
  const float* queries  = (const float*)d_in[1];
  const float* values   = (const float*)d_in[2];
  const float* original = (const float*)d_in[3];
  float* out = (float*)d_out;

  const size_t PREPB = (size_t)BB * 128 * 32768;   // 16,777,216

  // Tier ladder: smaller chunks = shorter critical chains = more parallelism.
  // need(CC) = PREP + slots*64KB (O' fp16) + slots*512B (m,l).
  // CC=32:35.80M  CC=40:32.10M  CC=48:29,458,432 (proven floor)  CC=64:25.26M
  const int CCcand[5] = {32, 40, 48, 64, 128};
  int CC = 128, TSLOT = 0, units = NTQ;
  for (int i = 0; i < 5; ++i) {
    int cc = CCcand[i];
    int un = 0, sl = 0;
    for (int t = 0; t < NTQ; ++t) {
      int rt = rt_of(t, cc);
      un += rt;
      if (rt >= 2) sl += rt;
    }
    size_t need = PREPB + (size_t)BB * sl * (64 * 512 * 2)
                        + (size_t)BB * sl * (64 * 8);
    if (ws_size >= need) { CC = cc; TSLOT = sl; units = un; break; }
  }

  char* PREP = (char*)d_ws;
  _Float16* Opart = (_Float16*)(PREP + PREPB);
  float* MLp = (float*)(PREP + PREPB + (size_t)BB * TSLOT * (64 * 512 * 2));

  hipLaunchKernelGGL(prep_kernel, dim3(BB * 128), dim3(256), 0, stream,
                     keys, values, PREP);

  hipLaunchKernelGGL(attn_kernel, dim3(BB * units), dim3(256), 0, stream,
                     PREP, queries, Opart, MLp, out, CC, TSLOT);

  const int cgrid = (BB * SS * 128) / 256;   // 4096 blocks
  hipLaunchKernelGGL(combine_kernel, dim3(cgrid), dim3(256), 0, stream,
                     Opart, MLp, original, out, CC, TSLOT);
}

// Round 6
// 97.167 us; speedup vs baseline: 2.0880x; 1.1184x over previous
//
#include <hip/hip_runtime.h>
#include <stdint.h>

#define BB 4
#define SS 2048
#define DD 512
#define NTQ 32            // S/64 q-tiles per batch
#define NEG_BIG -1e30f
#define RESC_THR 4.0f     // defer-max threshold
#define CAPOUT 256        // O' slots that fit in out[...,0:512] halves

typedef __attribute__((ext_vector_type(4))) float f32x4;
typedef __attribute__((ext_vector_type(8))) _Float16 f16x8;
typedef __attribute__((ext_vector_type(4))) _Float16 f16x4;

typedef __attribute__((address_space(1))) void GV;
typedef __attribute__((address_space(3))) void LV;

union PK4 { _Float16 h[4]; uint2 u; };

// chunks per q-tile t for chunk size CC (in 16-kv tiles)
__device__ __host__ __forceinline__ int rt_of(int t, int CC) {
  return (4 * (t + 1) + CC - 1) / CC;
}

// O' slot location: first CAPOUT slots live in the out[...,0:512] halves
// (32 rows x 2KB, chunk stride 4096B); the rest in ws (contiguous, stride 2048).
__device__ __forceinline__ char* slot_base(float* Out, char* wsOp, int s, int& stride) {
  if (s < CAPOUT) { stride = 4096; return (char*)Out + (size_t)s * 131072; }
  stride = 2048;  return wsOp + (size_t)(s - CAPOUT) * 65536;
}

// ---------------------------------------------------------------------------
// Prep: K -> fp16 tile images in exact LDS byte layout (XOR swizzle baked in),
//       V -> pair-transposed fp16 images. One (b, 16-kv-tile) per block.
// K image:  byte = rr*1024 + ((cc*2) ^ ((rr&7)<<4))
// V image:  d -> e=d>>5, mm=d&15, p=(d>>4)&1;
//           byte = 16384 + e*1024 + mm*64 + ((kq4^(mm&3))&3)*16 + p*8
//           (so one b128 read gives both d-halves for an acc pair; bank-uniform)
// ---------------------------------------------------------------------------
__global__ __launch_bounds__(256)
void prep_kernel(const float* __restrict__ K, const float* __restrict__ V,
                 char* __restrict__ PREP)
{
  const int blk = blockIdx.x;
  const int b   = blk >> 7;
  const int j   = blk & 127;
  const int tid = threadIdx.x;
  char* img = PREP + (size_t)blk * 32768;

  #pragma unroll
  for (int i = 0; i < 8; ++i) {
    int chunk = tid + 256 * i;
    int rr = chunk >> 7;
    int cc = (chunk & 127) << 2;
    float4 a = *(const float4*)(K + ((size_t)(b * SS + j * 16 + rr)) * DD + cc);
    PK4 p; p.h[0] = (_Float16)a.x; p.h[1] = (_Float16)a.y;
           p.h[2] = (_Float16)a.z; p.h[3] = (_Float16)a.w;
    int off = rr * 1024 + ((cc * 2) ^ ((rr & 7) << 4));
    *(uint2*)(img + off) = p.u;
  }

  #pragma unroll
  for (int half = 0; half < 2; ++half) {
    int d = tid + 256 * half;
    const float* vp = V + ((size_t)(b * SS + j * 16)) * DD + d;
    int e = d >> 5, mm = d & 15, p = (d >> 4) & 1;
    #pragma unroll
    for (int kq4 = 0; kq4 < 4; ++kq4) {
      PK4 pk;
      pk.h[0] = (_Float16)vp[(kq4 * 4 + 0) * DD];
      pk.h[1] = (_Float16)vp[(kq4 * 4 + 1) * DD];
      pk.h[2] = (_Float16)vp[(kq4 * 4 + 2) * DD];
      pk.h[3] = (_Float16)vp[(kq4 * 4 + 3) * DD];
      int slot = (kq4 ^ (mm & 3)) & 3;
      *(uint2*)(img + 16384 + e * 1024 + mm * 64 + slot * 16 + p * 8) = pk.u;
    }
  }
}

// ---------------------------------------------------------------------------
// Flash attention over fixed-size kv chunks (CC 16-row tiles per chunk).
// Unit = (t, b, r); decode order: t desc (longest first), r, then b fastest
// (bid % 4 == b -> each batch's PREP pinned to 2 XCDs' L2).
// Rt==1 units write normalized fp32 output directly; Rt>=2 write (O', m, l)
// to slot b*TSLOT + OFF(t) + r (slots live in out-left-halves then ws).
// ---------------------------------------------------------------------------
__global__ __launch_bounds__(256, 2)
void attn_kernel(const char* __restrict__ PREP, const float* __restrict__ Qg,
                 char* __restrict__ wsOp, float* __restrict__ MLp,
                 float* __restrict__ Out, int CC, int TSLOT)
{
  __shared__ char smem[2][32768];   // [K 16KB][VT 16KB] per buffer

  const int tid = threadIdx.x;
  const int ln  = tid & 63;
  const int w   = tid >> 6;
  const int m   = ln & 15;
  const int g   = ln >> 4;

  // ---- decode blockIdx -> (t, b, r), t descending, b fastest ----------------
  int t = 0, b = 0, r = 0;
  {
    int u = blockIdx.x, base = 0;
    for (int tt = NTQ - 1; tt >= 0; --tt) {
      int rt = rt_of(tt, CC);
      int cnt = BB * rt;
      if (u < base + cnt) { int loc = u - base; t = tt; r = loc / BB; b = loc % BB; break; }
      base += cnt;
    }
  }
  const int Rt     = rt_of(t, CC);
  const int direct = (Rt == 1);

  const int T16 = 4 * (t + 1);
  const int j0  = r * CC;
  const int j1  = min(j0 + CC, T16);
  const int nt  = j1 - j0;          // >= 1 by construction

  int slot = 0;
  if (!direct) {
    int off = 0;
    for (int tt = 0; tt < t; ++tt) {
      int rt = rt_of(tt, CC);
      if (rt >= 2) off += rt;
    }
    slot = b * TSLOT + off + r;
  }

  const int qrow  = t * 64 + w * 16 + m;
  const int qmaxw = t * 64 + w * 16 + 15;

  // ---- Q fp32 -> fp16 fragments (once per block) ---------------------------
  f16x8 qf[16];
  {
    const float* qp = Qg + ((size_t)(b * SS + qrow)) * DD + g * 8;
    #pragma unroll
    for (int ks = 0; ks < 16; ++ks) {
      float4 a0 = *(const float4*)(qp + ks * 32);
      float4 a1 = *(const float4*)(qp + ks * 32 + 4);
      f16x8 v;
      v[0] = (_Float16)a0.x; v[1] = (_Float16)a0.y;
      v[2] = (_Float16)a0.z; v[3] = (_Float16)a0.w;
      v[4] = (_Float16)a1.x; v[5] = (_Float16)a1.y;
      v[6] = (_Float16)a1.z; v[7] = (_Float16)a1.w;
      qf[ks] = v;
    }
  }

  f32x4 acc[32];
  {
    f32x4 z = {0.f, 0.f, 0.f, 0.f};
    #pragma unroll
    for (int i = 0; i < 32; ++i) acc[i] = z;
  }
  float mst = NEG_BIG, lst = 0.f;

  const char* tilebase = PREP + (size_t)b * 128 * 32768;

  auto STAGE = [&](int bi, int jt) {
    const char* src = tilebase + (size_t)jt * 32768;
    #pragma unroll
    for (int i = 0; i < 8; ++i) {
      int o = (tid + i * 256) * 16;
      __builtin_amdgcn_global_load_lds((GV*)(src + o), (LV*)(smem[bi] + o),
                                       16, 0, 0);
    }
  };

  STAGE(0, j0);

  const int vs = ((g ^ (m & 3)) & 3) * 16;   // V slot offset (per-lane const)

  for (int jj = 0; jj < nt; ++jj) {
    const int cur = jj & 1;
    __syncthreads();                       // buf[cur] staged (issued last iter)
    if (jj + 1 < nt) STAGE(cur ^ 1, j0 + jj + 1);

    const int kv0 = (j0 + jj) * 16;
    if (kv0 <= qmaxw) {                    // causal early-out (wave-uniform)
      const char* kb = smem[cur];

      // ---- QK^T: S^T[kv][q], fp16, split accumulators (dep chain 16->8) ----
      f32x4 s0 = {0.f, 0.f, 0.f, 0.f};
      f32x4 s1 = {0.f, 0.f, 0.f, 0.f};
      {
        const char* krow = kb + m * 1024;
        const int rsw = (m & 7) << 4;
        __builtin_amdgcn_s_setprio(1);
        #pragma unroll
        for (int kk = 0; kk < 8; ++kk) {
          int offA = ((2 * kk) * 64 + g * 16) ^ rsw;
          int offB = ((2 * kk + 1) * 64 + g * 16) ^ rsw;
          f16x8 ka = *(const f16x8*)(krow + offA);
          f16x8 kb2 = *(const f16x8*)(krow + offB);
          s0 = __builtin_amdgcn_mfma_f32_16x16x32_f16(ka,  qf[2 * kk],     s0, 0, 0, 0);
          s1 = __builtin_amdgcn_mfma_f32_16x16x32_f16(kb2, qf[2 * kk + 1], s1, 0, 0, 0);
        }
        __builtin_amdgcn_s_setprio(0);
      }
      f32x4 s;
      s[0] = s0[0] + s1[0]; s[1] = s0[1] + s1[1];
      s[2] = s0[2] + s1[2]; s[3] = s0[3] + s1[3];

      // ---- online softmax (lane: kv = kv0+4g+e, q = qrow) -----------------
      float sv0 = (kv0 + 4 * g + 0 <= qrow) ? s[0] : NEG_BIG;
      float sv1 = (kv0 + 4 * g + 1 <= qrow) ? s[1] : NEG_BIG;
      float sv2 = (kv0 + 4 * g + 2 <= qrow) ? s[2] : NEG_BIG;
      float sv3 = (kv0 + 4 * g + 3 <= qrow) ? s[3] : NEG_BIG;
      float tm = fmaxf(fmaxf(sv0, sv1), fmaxf(sv2, sv3));
      tm = fmaxf(tm, __shfl_xor(tm, 16));
      tm = fmaxf(tm, __shfl_xor(tm, 32));

      float sc = 1.f;
      unsigned long long need = __ballot(tm > mst + RESC_THR);
      if (need) {                          // wave-uniform, rare (defer-max)
        float mnew = fmaxf(mst, tm);
        sc = __expf(mst - mnew);
        mst = mnew;
        #pragma unroll
        for (int i = 0; i < 32; ++i) {
          acc[i][0] *= sc; acc[i][1] *= sc; acc[i][2] *= sc; acc[i][3] *= sc;
        }
      }
      float p0 = (kv0 + 4 * g + 0 <= qrow) ? __expf(sv0 - mst) : 0.f;
      float p1 = (kv0 + 4 * g + 1 <= qrow) ? __expf(sv1 - mst) : 0.f;
      float p2 = (kv0 + 4 * g + 2 <= qrow) ? __expf(sv2 - mst) : 0.f;
      float p3 = (kv0 + 4 * g + 3 <= qrow) ? __expf(sv3 - mst) : 0.f;
      float rs = p0 + p1 + p2 + p3;
      rs += __shfl_xor(rs, 16);
      rs += __shfl_xor(rs, 32);
      lst = lst * sc + rs;

      // ---- PV: O^T += V^T * P^T; paired b128 V reads feed 2 MFMAs ---------
      f16x4 pf;
      pf[0] = (_Float16)p0; pf[1] = (_Float16)p1;
      pf[2] = (_Float16)p2; pf[3] = (_Float16)p3;
      const char* vb = kb + 16384;
      __builtin_amdgcn_s_setprio(1);
      #pragma unroll
      for (int e = 0; e < 16; ++e) {
        f16x8 vv = *(const f16x8*)(vb + e * 1024 + m * 64 + vs);
        f16x4 vlo; vlo[0] = vv[0]; vlo[1] = vv[1]; vlo[2] = vv[2]; vlo[3] = vv[3];
        f16x4 vhi; vhi[0] = vv[4]; vhi[1] = vv[5]; vhi[2] = vv[6]; vhi[3] = vv[7];
        acc[2 * e]     = __builtin_amdgcn_mfma_f32_16x16x16f16(vlo, pf, acc[2 * e],     0, 0, 0);
        acc[2 * e + 1] = __builtin_amdgcn_mfma_f32_16x16x16f16(vhi, pf, acc[2 * e + 1], 0, 0, 0);
      }
      __builtin_amdgcn_s_setprio(0);
    }
  }

  // ---- epilogue -------------------------------------------------------------
  if (direct) {
    float inv = 1.0f / lst;
    float* orow = Out + ((size_t)(b * SS + qrow)) * 1024 + 512;
    #pragma unroll
    for (int dt = 0; dt < 32; ++dt) {
      float4 v4;
      v4.x = acc[dt][0] * inv; v4.y = acc[dt][1] * inv;
      v4.z = acc[dt][2] * inv; v4.w = acc[dt][3] * inv;
      *(float4*)(orow + dt * 16 + g * 4) = v4;
    }
  } else {
    const int q = w * 16 + m;
    if (ln < 16) {
      float* mlp = MLp + ((size_t)slot * 64 + q) * 2;
      mlp[0] = mst; mlp[1] = lst;
    }
    int stride; char* sb = slot_base(Out, wsOp, slot, stride);
    char* rowb = sb + (size_t)(q >> 1) * stride + (q & 1) * 1024;
    #pragma unroll
    for (int dt = 0; dt < 32; ++dt) {
      PK4 p;
      p.h[0] = (_Float16)acc[dt][0]; p.h[1] = (_Float16)acc[dt][1];
      p.h[2] = (_Float16)acc[dt][2]; p.h[3] = (_Float16)acc[dt][3];
      *(uint2*)(rowb + dt * 32 + g * 8) = p.u;
    }
  }
}

// ---------------------------------------------------------------------------
// Combine: merges partial (O', m, l) for q-tiles with Rt >= 2 and writes
// out[...,512:1024]. Does NOT touch out[...,0:512] (slots may live there);
// copy_orig runs after and fills the left halves.
// ---------------------------------------------------------------------------
__global__ __launch_bounds__(256)
void combine_kernel(char* __restrict__ wsOp, const float* __restrict__ MLp,
                    float* __restrict__ Out, int CC, int TSLOT)
{
  int gid = blockIdx.x * 256 + threadIdx.x;
  int row = gid >> 7;
  int c4  = (gid & 127) << 2;
  int b = row >> 11;
  int s = row & 2047;
  int t = s >> 6;
  int qloc = s & 63;

  const int Rt = rt_of(t, CC);
  if (Rt < 2) return;                       // direct-written by attn_kernel

  int off = 0;
  for (int tt = 0; tt < t; ++tt) {
    int rt = rt_of(tt, CC);
    if (rt >= 2) off += rt;
  }
  const int base = b * TSLOT + off;

  float mr[8], lr[8];
  #pragma unroll
  for (int rr = 0; rr < 8; ++rr) { mr[rr] = NEG_BIG; lr[rr] = 0.f; }
  #pragma unroll
  for (int rr = 0; rr < 8; ++rr) {
    if (rr < Rt) {
      const float* p = MLp + ((size_t)(base + rr) * 64 + qloc) * 2;
      mr[rr] = p[0]; lr[rr] = p[1];
    }
  }
  float M = NEG_BIG;
  #pragma unroll
  for (int rr = 0; rr < 8; ++rr) M = fmaxf(M, mr[rr]);

  float L = 0.f, a0 = 0.f, a1 = 0.f, a2 = 0.f, a3 = 0.f;
  #pragma unroll
  for (int rr = 0; rr < 8; ++rr) {
    if (rr < Rt && mr[rr] > -5e29f) {       // skip rows empty in this chunk
      float wgt = __expf(mr[rr] - M);
      L += wgt * lr[rr];
      int stride; char* sb = slot_base(Out, wsOp, base + rr, stride);
      const char* op = sb + (size_t)(qloc >> 1) * stride + (qloc & 1) * 1024 + c4 * 2;
      f16x4 ov = *(const f16x4*)op;
      a0 += wgt * (float)ov[0]; a1 += wgt * (float)ov[1];
      a2 += wgt * (float)ov[2]; a3 += wgt * (float)ov[3];
    }
  }
  float inv = 1.0f / L;
  float4 r4; r4.x = a0 * inv; r4.y = a1 * inv; r4.z = a2 * inv; r4.w = a3 * inv;
  *(float4*)(Out + (size_t)row * 1024 + 512 + c4) = r4;
}

__global__ __launch_bounds__(256)
void copy_orig(const float* __restrict__ orig, float* __restrict__ Out)
{
  int gid = blockIdx.x * 256 + threadIdx.x;
  int row = gid >> 7;
  int c4  = (gid & 127) << 2;
  *(float4*)(Out + (size_t)row * 1024 + c4) = *(const float4*)(orig + (size_t)row * 512 + c4);
}

extern "C" void kernel_launch(void* const* d_in, const int* in_sizes, int n_in,
                              void* d_out, int out_size, void* d_ws, size_t ws_size,
                              hipStream_t stream)
{
  (void)in_sizes; (void)n_in; (void)out_size;
  const float* keys     = (const float*)d_in[0];
  const float* queries  = (const float*)d_in[1];
  const float* values   = (const float*)d_in[2];
  const float* original = (const float*)d_in[3];
  float* out = (float*)d_out;

  const size_t PREPB = (size_t)BB * 128 * 32768;   // 16,777,216
  const size_t MLRES = 512 * 512;                  // 262,144 (<=512 slots x 512B)

  // slot capacity: 256 slots hidden in out[...,0:512] + whatever ws holds
  long nWs = (ws_size > PREPB + MLRES) ? (long)((ws_size - PREPB - MLRES) / 65536) : 0;
  long cap = CAPOUT + nWs;

  const int CCcand[8] = {20, 24, 28, 32, 40, 48, 64, 128};
  int CC = 128, TSLOT = 0, units = NTQ;
  for (int i = 0; i < 8; ++i) {
    int cc = CCcand[i];
    int un = 0, sl = 0;
    for (int t = 0; t < NTQ; ++t) {
      int rt = rt_of(t, cc);
      un += rt;
      if (rt >= 2) sl += rt;
    }
    long total = (long)BB * sl;
    if (total <= cap && total <= 512) { CC = cc; TSLOT = sl; units = un; break; }
  }

  char* PREP = (char*)d_ws;
  float* MLp = (float*)(PREP + PREPB);
  char* wsOp = PREP + PREPB + MLRES;

  hipLaunchKernelGGL(prep_kernel, dim3(BB * 128), dim3(256), 0, stream,
                     keys, values, PREP);

  hipLaunchKernelGGL(attn_kernel, dim3(BB * units), dim3(256), 0, stream,
                     PREP, queries, wsOp, MLp, out, CC, TSLOT);

  const int cgrid = (BB * SS * 128) / 256;   // 4096 blocks
  hipLaunchKernelGGL(combine_kernel, dim3(cgrid), dim3(256), 0, stream,
                     wsOp, MLp, out, CC, TSLOT);
  hipLaunchKernelGGL(copy_orig, dim3(cgrid), dim3(256), 0, stream, original, out);
}